// Round 5
// baseline (2890.656 us; speedup 1.0000x reference)
//
#include <hip/hip_runtime.h>

// GCN: 4x [h=(x*ns)@W ; agg=segment_sum(h[src],dst) ; out=agg*nd+b (+relu)]
// N=100000 nodes, E=1.6M edges, feats 128->64->64->64->40, fp32.
// R5: bin-level edge partition (128 nodes/bin, cap 3072) replaces node-CSR:
//     binfill = 1 pass (LDS bin hist + per-(block,bin) reserve + clustered
//     scatter of packed codes); agg_bin = LDS accumulator per 128-node bin
//     with in-LDS in-degree histogram (nd computed on the fly).

constexpr int BLK = 256;
constexpr int BIN_SHIFT = 7;          // 128 nodes per bin
constexpr int BIN_NODES = 128;
constexpr int BIN_CAP = 3072;         // mean load 2048, +22 sigma headroom
constexpr int MAX_NB = 800;           // LDS hist capacity (nb = 782)
constexpr int EPT = 32;               // edges per thread in binfill

__global__ void zero_int(int* p, int n) {
  int i = blockIdx.x * blockDim.x + threadIdx.x;
  if (i < n) p[i] = 0;
}

// ---- single-pass edge binning + out-degree count ----
__global__ __launch_bounds__(BLK) void binfill(const int* __restrict__ src,
                                               const int* __restrict__ dst,
                                               int* __restrict__ deg_out,
                                               int* __restrict__ bin_cnt,
                                               int* __restrict__ codes,
                                               int e, int nb) {
  __shared__ int hist[MAX_NB];
  __shared__ int basec[MAX_NB];
  const int tid = threadIdx.x;
  for (int i = tid; i < nb; i += BLK) hist[i] = 0;
  __syncthreads();

  const int B0 = blockIdx.x * (BLK * EPT);
  int s[EPT], d[EPT];
  #pragma unroll
  for (int c = 0; c < EPT / 4; ++c) {
    int i = B0 + (c * BLK + tid) * 4;
    if (i + 3 < e) {
      int4 sv = *(const int4*)(src + i);
      int4 dv = *(const int4*)(dst + i);
      s[4 * c + 0] = sv.x; s[4 * c + 1] = sv.y;
      s[4 * c + 2] = sv.z; s[4 * c + 3] = sv.w;
      d[4 * c + 0] = dv.x; d[4 * c + 1] = dv.y;
      d[4 * c + 2] = dv.z; d[4 * c + 3] = dv.w;
    } else {
      #pragma unroll
      for (int j = 0; j < 4; ++j) {
        int ii = i + j;
        if (ii < e) { s[4 * c + j] = src[ii]; d[4 * c + j] = dst[ii]; }
        else { s[4 * c + j] = 0; d[4 * c + j] = -1; }
      }
    }
  }

  #pragma unroll
  for (int j = 0; j < EPT; ++j) {
    if (d[j] >= 0) {
      atomicAdd(&deg_out[s[j]], 1);
      atomicAdd(&hist[d[j] >> BIN_SHIFT], 1);
    }
  }
  __syncthreads();
  for (int i = tid; i < nb; i += BLK) {
    int c = hist[i];
    basec[i] = c ? atomicAdd(&bin_cnt[i], c) : 0;
  }
  __syncthreads();
  #pragma unroll
  for (int j = 0; j < EPT; ++j) {
    if (d[j] >= 0) {
      int b = d[j] >> BIN_SHIFT;
      int ofs = atomicAdd(&basec[b], 1);
      if (ofs < BIN_CAP)
        codes[(size_t)b * BIN_CAP + ofs] = ((d[j] & (BIN_NODES - 1)) << 17) | s[j];
    }
  }
}

__global__ void norms_ns(const int* __restrict__ deg_out, float* ns, int n) {
  int i = blockIdx.x * blockDim.x + threadIdx.x;
  if (i < n) {
    int od = deg_out[i];
    ns[i] = od > 0 ? rsqrtf((float)od) : 0.f;
  }
}

// ---- h = (x*ns) @ W ; block-tiled GEMM (R4 design, unchanged) ----
template <int K, int F, int STRIDE>
__global__ __launch_bounds__(BLK) void gemm_tile(const float* __restrict__ x,
                                                 const float* __restrict__ W,
                                                 const float* __restrict__ ns,
                                                 float* __restrict__ h, int n) {
  constexpr int KT = 64;
  constexpr int KP = KT + 4;
  __shared__ float sx[64 * KP];
  __shared__ float sW[KT * F];
  const int tid = threadIdx.x;
  const int n0 = blockIdx.x * 64;
  const int ft = tid & 15, nt = tid >> 4;
  const int fbase = (4 * ft < F) ? 4 * ft : 0;
  float acc[4][4] = {};

  for (int kt = 0; kt < K; kt += KT) {
    if (kt) __syncthreads();
    for (int i = tid; i < KT * F; i += BLK) sW[i] = W[kt * F + i];
    for (int idx = tid; idx < 64 * (KT / 4); idx += BLK) {
      int node = idx >> 4;
      int kk = idx & 15;
      int gn = min(n0 + node, n - 1);
      float4 v = *(const float4*)(x + (size_t)gn * K + kt + kk * 4);
      *(float4*)(sx + node * KP + kk * 4) = v;
    }
    __syncthreads();

    #pragma unroll 4
    for (int k0 = 0; k0 < KT; k0 += 4) {
      float4 xv0 = *(const float4*)(sx + (4 * nt + 0) * KP + k0);
      float4 xv1 = *(const float4*)(sx + (4 * nt + 1) * KP + k0);
      float4 xv2 = *(const float4*)(sx + (4 * nt + 2) * KP + k0);
      float4 xv3 = *(const float4*)(sx + (4 * nt + 3) * KP + k0);
      float4 w0 = *(const float4*)(sW + (k0 + 0) * F + fbase);
      float4 w1 = *(const float4*)(sW + (k0 + 1) * F + fbase);
      float4 w2 = *(const float4*)(sW + (k0 + 2) * F + fbase);
      float4 w3 = *(const float4*)(sW + (k0 + 3) * F + fbase);
#define GCN_STEP(C, WV)                                                  \
      acc[0][0] = fmaf(xv0.C, WV.x, acc[0][0]);                          \
      acc[0][1] = fmaf(xv0.C, WV.y, acc[0][1]);                          \
      acc[0][2] = fmaf(xv0.C, WV.z, acc[0][2]);                          \
      acc[0][3] = fmaf(xv0.C, WV.w, acc[0][3]);                          \
      acc[1][0] = fmaf(xv1.C, WV.x, acc[1][0]);                          \
      acc[1][1] = fmaf(xv1.C, WV.y, acc[1][1]);                          \
      acc[1][2] = fmaf(xv1.C, WV.z, acc[1][2]);                          \
      acc[1][3] = fmaf(xv1.C, WV.w, acc[1][3]);                          \
      acc[2][0] = fmaf(xv2.C, WV.x, acc[2][0]);                          \
      acc[2][1] = fmaf(xv2.C, WV.y, acc[2][1]);                          \
      acc[2][2] = fmaf(xv2.C, WV.z, acc[2][2]);                          \
      acc[2][3] = fmaf(xv2.C, WV.w, acc[2][3]);                          \
      acc[3][0] = fmaf(xv3.C, WV.x, acc[3][0]);                          \
      acc[3][1] = fmaf(xv3.C, WV.y, acc[3][1]);                          \
      acc[3][2] = fmaf(xv3.C, WV.z, acc[3][2]);                          \
      acc[3][3] = fmaf(xv3.C, WV.w, acc[3][3]);
      GCN_STEP(x, w0)
      GCN_STEP(y, w1)
      GCN_STEP(z, w2)
      GCN_STEP(w, w3)
#undef GCN_STEP
    }
  }

  #pragma unroll
  for (int i = 0; i < 4; ++i) {
    int node = n0 + 4 * nt + i;
    if (node < n) {
      float s = ns[node];
      float4 o;
      if (4 * ft < F) {
        o.x = acc[i][0] * s; o.y = acc[i][1] * s;
        o.z = acc[i][2] * s; o.w = acc[i][3] * s;
      } else {
        o.x = o.y = o.z = o.w = 0.f;
      }
      *(float4*)(h + (size_t)node * STRIDE + 4 * ft) = o;
    }
  }
}

// ---- agg: one block per 128-node bin; LDS accumulator + in-degree hist.
// 4 edges/wave-iter: group g=lane>>4 takes edge k, 16 lanes x float4 = row.
template <bool RELU, int OUTF>
__global__ __launch_bounds__(BLK) void agg_bin(const float* __restrict__ h,
                                               const int* __restrict__ codes,
                                               const int* __restrict__ bin_cnt,
                                               const float* __restrict__ bias,
                                               float* __restrict__ out, int n) {
  __shared__ float sacc[BIN_NODES * 64];
  __shared__ int shist[BIN_NODES];
  const int tid = threadIdx.x;
  #pragma unroll
  for (int i = 0; i < (BIN_NODES * 64 / 4) / BLK; ++i)
    ((float4*)sacc)[tid + i * BLK] = float4{0.f, 0.f, 0.f, 0.f};
  if (tid < BIN_NODES) shist[tid] = 0;
  __syncthreads();

  const int bin = blockIdx.x;
  const int cnt = min(bin_cnt[bin], BIN_CAP);
  const int* cb = codes + (size_t)bin * BIN_CAP;
  const int lane = tid & 63, w = tid >> 6;
  const int g = lane >> 4, fl = lane & 15;

  #pragma unroll 4
  for (int k = w * 4 + g; k < cnt; k += 16) {
    int code = cb[k];
    int srcn = code & 0x1FFFF;
    int dloc = code >> 17;
    float4 v = *(const float4*)(h + (size_t)srcn * 64 + fl * 4);
    float* a = sacc + dloc * 64 + fl * 4;
    atomicAdd(a + 0, v.x);
    atomicAdd(a + 1, v.y);
    atomicAdd(a + 2, v.z);
    atomicAdd(a + 3, v.w);
    if (fl == 0) atomicAdd(&shist[dloc], 1);
  }
  __syncthreads();

  const int nloc = tid >> 1;
  const int f0 = (tid & 1) * 32;
  const int node = bin * BIN_NODES + nloc;
  if (node < n) {
    int c = shist[nloc];
    float ndv = c > 0 ? rsqrtf((float)c) : 0.f;
    #pragma unroll
    for (int q = 0; q < 8; ++q) {
      int f = f0 + q * 4;
      if (f < OUTF) {
        float4 a = *(float4*)(sacc + nloc * 64 + f);
        float4 bv = *(const float4*)(bias + f);
        float4 o;
        o.x = a.x * ndv + bv.x;
        o.y = a.y * ndv + bv.y;
        o.z = a.z * ndv + bv.z;
        o.w = a.w * ndv + bv.w;
        if (RELU) {
          o.x = fmaxf(o.x, 0.f); o.y = fmaxf(o.y, 0.f);
          o.z = fmaxf(o.z, 0.f); o.w = fmaxf(o.w, 0.f);
        }
        *(float4*)(out + (size_t)node * OUTF + f) = o;
      }
    }
  }
}

extern "C" void kernel_launch(void* const* d_in, const int* in_sizes, int n_in,
                              void* d_out, int out_size, void* d_ws, size_t ws_size,
                              hipStream_t stream) {
  const float* features = (const float*)d_in[0];
  const int* src = (const int*)d_in[1];
  const int* dst = (const int*)d_in[2];
  const float* W0 = (const float*)d_in[3];
  const float* b0 = (const float*)d_in[4];
  const float* W1 = (const float*)d_in[5];
  const float* b1 = (const float*)d_in[6];
  const float* W2 = (const float*)d_in[7];
  const float* b2 = (const float*)d_in[8];
  const float* W3 = (const float*)d_in[9];
  const float* b3 = (const float*)d_in[10];

  const int n = in_sizes[0] / 128;  // 100000
  const int e = in_sizes[1];        // 1600000
  const int nb = (n + BIN_NODES - 1) >> BIN_SHIFT;  // 782

  char* p = (char*)d_ws;
  auto alloc = [&](size_t bytes) {
    void* q = (void*)p;
    p += (bytes + 255) & ~(size_t)255;
    return q;
  };
  int* deg_out = (int*)alloc((size_t)(n + nb) * 4);  // deg_out + bin_cnt
  int* bin_cnt = deg_out + n;
  float* ns = (float*)alloc((size_t)n * 4);
  int* codes = (int*)alloc((size_t)nb * BIN_CAP * 4);
  float* h = (float*)alloc((size_t)n * 64 * 4);
  float* xb = (float*)alloc((size_t)n * 64 * 4);

  zero_int<<<(n + nb + BLK - 1) / BLK, BLK, 0, stream>>>(deg_out, n + nb);
  binfill<<<(e + BLK * EPT - 1) / (BLK * EPT), BLK, 0, stream>>>(
      src, dst, deg_out, bin_cnt, codes, e, nb);
  norms_ns<<<(n + BLK - 1) / BLK, BLK, 0, stream>>>(deg_out, ns, n);

  const int gblk = (n + 63) / 64;  // gemm_tile: 64 nodes per block

  // layer 0: 128 -> 64, relu
  gemm_tile<128, 64, 64><<<gblk, BLK, 0, stream>>>(features, W0, ns, h, n);
  agg_bin<true, 64><<<nb, BLK, 0, stream>>>(h, codes, bin_cnt, b0, xb, n);
  // layer 1: 64 -> 64, relu
  gemm_tile<64, 64, 64><<<gblk, BLK, 0, stream>>>(xb, W1, ns, h, n);
  agg_bin<true, 64><<<nb, BLK, 0, stream>>>(h, codes, bin_cnt, b1, xb, n);
  // layer 2: 64 -> 64, relu
  gemm_tile<64, 64, 64><<<gblk, BLK, 0, stream>>>(xb, W2, ns, h, n);
  agg_bin<true, 64><<<nb, BLK, 0, stream>>>(h, codes, bin_cnt, b2, xb, n);
  // layer 3: 64 -> 40, no relu (h padded to stride 64)
  gemm_tile<64, 40, 64><<<gblk, BLK, 0, stream>>>(xb, W3, ns, h, n);
  agg_bin<false, 40><<<nb, BLK, 0, stream>>>(h, codes, bin_cnt, b3, (float*)d_out, n);
}

// Round 6
// 429.242 us; speedup vs baseline: 6.7343x; 6.7343x over previous
//
#include <hip/hip_runtime.h>

// GCN: 4x [h=(x*ns)@W ; agg=segment_sum(h[src],dst) ; out=agg*nd+b (+relu)]
// N=100000 nodes, E=1.6M edges, feats 128->64->64->64->40, fp32.
// R6: CSR built via bin pipeline (binfill -> scan_bins -> bin2csr) replacing
//     contended node-cursor atomics + random 4B scatter. Aggregation is the
//     proven R4 gather (agg4: 4 edges/wave-iter, 16 lanes x float4 per row).

constexpr int BLK = 256;
constexpr int BIN_SHIFT = 7;          // 128 nodes per bin
constexpr int BIN_NODES = 128;
constexpr int BIN_CAP = 3072;         // mean load 2048, +22 sigma headroom
constexpr int MAX_NB = 800;           // LDS hist capacity (nb = 782)
constexpr int EPT = 32;               // edges per thread in binfill

__global__ void zero_int(int* p, int n) {
  int i = blockIdx.x * blockDim.x + threadIdx.x;
  if (i < n) p[i] = 0;
}

// ---- single-pass edge binning + out-degree count ----
__global__ __launch_bounds__(BLK) void binfill(const int* __restrict__ src,
                                               const int* __restrict__ dst,
                                               int* __restrict__ deg_out,
                                               int* __restrict__ bin_cnt,
                                               int* __restrict__ codes,
                                               int e, int nb) {
  __shared__ int hist[MAX_NB];
  __shared__ int basec[MAX_NB];
  const int tid = threadIdx.x;
  for (int i = tid; i < nb; i += BLK) hist[i] = 0;
  __syncthreads();

  const int B0 = blockIdx.x * (BLK * EPT);
  int s[EPT], d[EPT];
  #pragma unroll
  for (int c = 0; c < EPT / 4; ++c) {
    int i = B0 + (c * BLK + tid) * 4;
    if (i + 3 < e) {
      int4 sv = *(const int4*)(src + i);
      int4 dv = *(const int4*)(dst + i);
      s[4 * c + 0] = sv.x; s[4 * c + 1] = sv.y;
      s[4 * c + 2] = sv.z; s[4 * c + 3] = sv.w;
      d[4 * c + 0] = dv.x; d[4 * c + 1] = dv.y;
      d[4 * c + 2] = dv.z; d[4 * c + 3] = dv.w;
    } else {
      #pragma unroll
      for (int j = 0; j < 4; ++j) {
        int ii = i + j;
        if (ii < e) { s[4 * c + j] = src[ii]; d[4 * c + j] = dst[ii]; }
        else { s[4 * c + j] = 0; d[4 * c + j] = -1; }
      }
    }
  }

  #pragma unroll
  for (int j = 0; j < EPT; ++j) {
    if (d[j] >= 0) {
      atomicAdd(&deg_out[s[j]], 1);
      atomicAdd(&hist[d[j] >> BIN_SHIFT], 1);
    }
  }
  __syncthreads();
  for (int i = tid; i < nb; i += BLK) {
    int c = hist[i];
    basec[i] = c ? atomicAdd(&bin_cnt[i], c) : 0;
  }
  __syncthreads();
  #pragma unroll
  for (int j = 0; j < EPT; ++j) {
    if (d[j] >= 0) {
      int b = d[j] >> BIN_SHIFT;
      int ofs = atomicAdd(&basec[b], 1);
      if (ofs < BIN_CAP)
        codes[(size_t)b * BIN_CAP + ofs] = ((d[j] & (BIN_NODES - 1)) << 17) | s[j];
    }
  }
}

__global__ void norms_ns(const int* __restrict__ deg_out, float* ns, int n) {
  int i = blockIdx.x * blockDim.x + threadIdx.x;
  if (i < n) {
    int od = deg_out[i];
    ns[i] = od > 0 ? rsqrtf((float)od) : 0.f;
  }
}

// ---- single-block exclusive scan of bin counts -> bin_base; row_ptr[n]=total
__global__ __launch_bounds__(BLK) void scan_bins(const int* __restrict__ bin_cnt,
                                                 int* __restrict__ bin_base,
                                                 int* __restrict__ row_ptr,
                                                 int nb, int n) {
  const int tid = threadIdx.x;
  const int base = tid * 4;
  int v0 = 0, v1 = 0, v2 = 0, v3 = 0;
  if (base + 0 < nb) v0 = min(bin_cnt[base + 0], BIN_CAP);
  if (base + 1 < nb) v1 = min(bin_cnt[base + 1], BIN_CAP);
  if (base + 2 < nb) v2 = min(bin_cnt[base + 2], BIN_CAP);
  if (base + 3 < nb) v3 = min(bin_cnt[base + 3], BIN_CAP);
  int s = v0 + v1 + v2 + v3;
  const int lane = tid & 63, wid = tid >> 6;
  int incl = s;
  #pragma unroll
  for (int off = 1; off < 64; off <<= 1) {
    int t = __shfl_up(incl, off, 64);
    if (lane >= off) incl += t;
  }
  __shared__ int wtot[4];
  if (lane == 63) wtot[wid] = incl;
  __syncthreads();
  int woff = 0;
  for (int w = 0; w < wid; ++w) woff += wtot[w];
  int run = woff + (incl - s);
  if (base + 0 < nb) bin_base[base + 0] = run; run += v0;
  if (base + 1 < nb) bin_base[base + 1] = run; run += v1;
  if (base + 2 < nb) bin_base[base + 2] = run; run += v2;
  if (base + 3 < nb) bin_base[base + 3] = run; run += v3;
  if (tid == BLK - 1) {
    int total = wtot[0] + wtot[1] + wtot[2] + wtot[3];
    bin_base[nb] = total;
    row_ptr[n] = total;
  }
}

// ---- one block per bin: local CSR build + row_ptr + nd ----
__global__ __launch_bounds__(BLK) void bin2csr(const int* __restrict__ codes,
                                               const int* __restrict__ bin_cnt,
                                               const int* __restrict__ bin_base,
                                               int* __restrict__ row_ptr,
                                               float* __restrict__ nd,
                                               int* __restrict__ esrc, int n) {
  __shared__ int scodes[BIN_CAP];
  __shared__ int hist[BIN_NODES];
  __shared__ int rowof[BIN_NODES];  // excl scan, then used as cursor
  __shared__ int wsum[2];
  const int tid = threadIdx.x;
  const int bin = blockIdx.x;
  const int cnt = min(bin_cnt[bin], BIN_CAP);
  const int base = bin_base[bin];
  const int* cb = codes + (size_t)bin * BIN_CAP;

  if (tid < BIN_NODES) hist[tid] = 0;
  for (int i = tid; i < cnt; i += BLK) scodes[i] = cb[i];
  __syncthreads();
  for (int i = tid; i < cnt; i += BLK) atomicAdd(&hist[scodes[i] >> 17], 1);
  __syncthreads();

  if (tid < BIN_NODES) {  // waves 0,1 fully active
    int v = hist[tid];
    int incl = v;
    const int lane = tid & 63, wid = tid >> 6;
    #pragma unroll
    for (int off = 1; off < 64; off <<= 1) {
      int t = __shfl_up(incl, off, 64);
      if (lane >= off) incl += t;
    }
    if (lane == 63) wsum[wid] = incl;
    __syncthreads();
    int excl = incl - v + (wid ? wsum[0] : 0);
    rowof[tid] = excl;
    int node = bin * BIN_NODES + tid;
    if (node < n) {
      row_ptr[node] = base + excl;
      nd[node] = v > 0 ? rsqrtf((float)v) : 0.f;
    }
  } else {
    __syncthreads();
  }
  __syncthreads();

  for (int i = tid; i < cnt; i += BLK) {
    int code = scodes[i];
    int pos = atomicAdd(&rowof[code >> 17], 1);
    esrc[base + pos] = code & 0x1FFFF;
  }
}

// ---- h = (x*ns) @ W ; block-tiled GEMM (R4 design, unchanged) ----
template <int K, int F, int STRIDE>
__global__ __launch_bounds__(BLK) void gemm_tile(const float* __restrict__ x,
                                                 const float* __restrict__ W,
                                                 const float* __restrict__ ns,
                                                 float* __restrict__ h, int n) {
  constexpr int KT = 64;
  constexpr int KP = KT + 4;
  __shared__ float sx[64 * KP];
  __shared__ float sW[KT * F];
  const int tid = threadIdx.x;
  const int n0 = blockIdx.x * 64;
  const int ft = tid & 15, nt = tid >> 4;
  const int fbase = (4 * ft < F) ? 4 * ft : 0;
  float acc[4][4] = {};

  for (int kt = 0; kt < K; kt += KT) {
    if (kt) __syncthreads();
    for (int i = tid; i < KT * F; i += BLK) sW[i] = W[kt * F + i];
    for (int idx = tid; idx < 64 * (KT / 4); idx += BLK) {
      int node = idx >> 4;
      int kk = idx & 15;
      int gn = min(n0 + node, n - 1);
      float4 v = *(const float4*)(x + (size_t)gn * K + kt + kk * 4);
      *(float4*)(sx + node * KP + kk * 4) = v;
    }
    __syncthreads();

    #pragma unroll 4
    for (int k0 = 0; k0 < KT; k0 += 4) {
      float4 xv0 = *(const float4*)(sx + (4 * nt + 0) * KP + k0);
      float4 xv1 = *(const float4*)(sx + (4 * nt + 1) * KP + k0);
      float4 xv2 = *(const float4*)(sx + (4 * nt + 2) * KP + k0);
      float4 xv3 = *(const float4*)(sx + (4 * nt + 3) * KP + k0);
      float4 w0 = *(const float4*)(sW + (k0 + 0) * F + fbase);
      float4 w1 = *(const float4*)(sW + (k0 + 1) * F + fbase);
      float4 w2 = *(const float4*)(sW + (k0 + 2) * F + fbase);
      float4 w3 = *(const float4*)(sW + (k0 + 3) * F + fbase);
#define GCN_STEP(C, WV)                                                  \
      acc[0][0] = fmaf(xv0.C, WV.x, acc[0][0]);                          \
      acc[0][1] = fmaf(xv0.C, WV.y, acc[0][1]);                          \
      acc[0][2] = fmaf(xv0.C, WV.z, acc[0][2]);                          \
      acc[0][3] = fmaf(xv0.C, WV.w, acc[0][3]);                          \
      acc[1][0] = fmaf(xv1.C, WV.x, acc[1][0]);                          \
      acc[1][1] = fmaf(xv1.C, WV.y, acc[1][1]);                          \
      acc[1][2] = fmaf(xv1.C, WV.z, acc[1][2]);                          \
      acc[1][3] = fmaf(xv1.C, WV.w, acc[1][3]);                          \
      acc[2][0] = fmaf(xv2.C, WV.x, acc[2][0]);                          \
      acc[2][1] = fmaf(xv2.C, WV.y, acc[2][1]);                          \
      acc[2][2] = fmaf(xv2.C, WV.z, acc[2][2]);                          \
      acc[2][3] = fmaf(xv2.C, WV.w, acc[2][3]);                          \
      acc[3][0] = fmaf(xv3.C, WV.x, acc[3][0]);                          \
      acc[3][1] = fmaf(xv3.C, WV.y, acc[3][1]);                          \
      acc[3][2] = fmaf(xv3.C, WV.z, acc[3][2]);                          \
      acc[3][3] = fmaf(xv3.C, WV.w, acc[3][3]);
      GCN_STEP(x, w0)
      GCN_STEP(y, w1)
      GCN_STEP(z, w2)
      GCN_STEP(w, w3)
#undef GCN_STEP
    }
  }

  #pragma unroll
  for (int i = 0; i < 4; ++i) {
    int node = n0 + 4 * nt + i;
    if (node < n) {
      float s = ns[node];
      float4 o;
      if (4 * ft < F) {
        o.x = acc[i][0] * s; o.y = acc[i][1] * s;
        o.z = acc[i][2] * s; o.w = acc[i][3] * s;
      } else {
        o.x = o.y = o.z = o.w = 0.f;
      }
      *(float4*)(h + (size_t)node * STRIDE + 4 * ft) = o;
    }
  }
}

// ---- agg: 4 edges per wave-iteration; h rows are stride-64 fp32.
// group g = lane>>4 handles edge k+g; 16 lanes x float4 = 256B row.
template <bool RELU, int OUTF>
__global__ void agg4(const float* __restrict__ h, const int* __restrict__ row_ptr,
                     const int* __restrict__ esrc, const float* __restrict__ nd,
                     const float* __restrict__ b, float* __restrict__ out, int n) {
  int tid = threadIdx.x;
  int node = blockIdx.x * 4 + (tid >> 6);
  if (node >= n) return;
  int lane = tid & 63;
  int g = lane >> 4;
  int fl = lane & 15;
  int beg = row_ptr[node], end = row_ptr[node + 1];
  float ax = 0.f, ay = 0.f, az = 0.f, aw = 0.f;
  #pragma unroll 4
  for (int k = beg + g; k < end; k += 4) {
    int s = esrc[k];
    float4 v = *(const float4*)(h + (size_t)s * 64 + fl * 4);
    ax += v.x; ay += v.y; az += v.z; aw += v.w;
  }
  ax += __shfl_xor(ax, 16, 64); ay += __shfl_xor(ay, 16, 64);
  az += __shfl_xor(az, 16, 64); aw += __shfl_xor(aw, 16, 64);
  ax += __shfl_xor(ax, 32, 64); ay += __shfl_xor(ay, 32, 64);
  az += __shfl_xor(az, 32, 64); aw += __shfl_xor(aw, 32, 64);
  if (lane < OUTF / 4) {
    float ndv = nd[node];
    float4 bv = ((const float4*)b)[fl];
    float4 o;
    o.x = ax * ndv + bv.x;
    o.y = ay * ndv + bv.y;
    o.z = az * ndv + bv.z;
    o.w = aw * ndv + bv.w;
    if (RELU) {
      o.x = fmaxf(o.x, 0.f); o.y = fmaxf(o.y, 0.f);
      o.z = fmaxf(o.z, 0.f); o.w = fmaxf(o.w, 0.f);
    }
    *(float4*)(out + (size_t)node * OUTF + fl * 4) = o;
  }
}

extern "C" void kernel_launch(void* const* d_in, const int* in_sizes, int n_in,
                              void* d_out, int out_size, void* d_ws, size_t ws_size,
                              hipStream_t stream) {
  const float* features = (const float*)d_in[0];
  const int* src = (const int*)d_in[1];
  const int* dst = (const int*)d_in[2];
  const float* W0 = (const float*)d_in[3];
  const float* b0 = (const float*)d_in[4];
  const float* W1 = (const float*)d_in[5];
  const float* b1 = (const float*)d_in[6];
  const float* W2 = (const float*)d_in[7];
  const float* b2 = (const float*)d_in[8];
  const float* W3 = (const float*)d_in[9];
  const float* b3 = (const float*)d_in[10];

  const int n = in_sizes[0] / 128;  // 100000
  const int e = in_sizes[1];        // 1600000
  const int nb = (n + BIN_NODES - 1) >> BIN_SHIFT;  // 782

  char* p = (char*)d_ws;
  auto alloc = [&](size_t bytes) {
    void* q = (void*)p;
    p += (bytes + 255) & ~(size_t)255;
    return q;
  };
  int* deg_out = (int*)alloc((size_t)(n + nb) * 4);  // deg_out + bin_cnt
  int* bin_cnt = deg_out + n;
  float* ns = (float*)alloc((size_t)n * 4);
  float* nd = (float*)alloc((size_t)n * 4);
  int* bin_base = (int*)alloc((size_t)(nb + 1) * 4);
  int* row_ptr = (int*)alloc((size_t)(n + 1) * 4);
  int* codes = (int*)alloc((size_t)nb * BIN_CAP * 4);
  int* esrc = (int*)alloc((size_t)e * 4);
  float* h = (float*)alloc((size_t)n * 64 * 4);
  float* xb = (float*)alloc((size_t)n * 64 * 4);

  zero_int<<<(n + nb + BLK - 1) / BLK, BLK, 0, stream>>>(deg_out, n + nb);
  binfill<<<(e + BLK * EPT - 1) / (BLK * EPT), BLK, 0, stream>>>(
      src, dst, deg_out, bin_cnt, codes, e, nb);
  norms_ns<<<(n + BLK - 1) / BLK, BLK, 0, stream>>>(deg_out, ns, n);
  scan_bins<<<1, BLK, 0, stream>>>(bin_cnt, bin_base, row_ptr, nb, n);
  bin2csr<<<nb, BLK, 0, stream>>>(codes, bin_cnt, bin_base, row_ptr, nd, esrc, n);

  const int gnode = (n + 3) / 4;   // agg4: 4 nodes (waves) per block
  const int gblk = (n + 63) / 64;  // gemm_tile: 64 nodes per block

  // layer 0: 128 -> 64, relu
  gemm_tile<128, 64, 64><<<gblk, BLK, 0, stream>>>(features, W0, ns, h, n);
  agg4<true, 64><<<gnode, BLK, 0, stream>>>(h, row_ptr, esrc, nd, b0, xb, n);
  // layer 1: 64 -> 64, relu
  gemm_tile<64, 64, 64><<<gblk, BLK, 0, stream>>>(xb, W1, ns, h, n);
  agg4<true, 64><<<gnode, BLK, 0, stream>>>(h, row_ptr, esrc, nd, b1, xb, n);
  // layer 2: 64 -> 64, relu
  gemm_tile<64, 64, 64><<<gblk, BLK, 0, stream>>>(xb, W2, ns, h, n);
  agg4<true, 64><<<gnode, BLK, 0, stream>>>(h, row_ptr, esrc, nd, b2, xb, n);
  // layer 3: 64 -> 40, no relu (h padded to stride 64)
  gemm_tile<64, 40, 64><<<gblk, BLK, 0, stream>>>(xb, W3, ns, h, n);
  agg4<false, 40><<<gnode, BLK, 0, stream>>>(h, row_ptr, esrc, nd, b3, (float*)d_out, n);
}

// Round 7
// 424.520 us; speedup vs baseline: 6.8092x; 1.0111x over previous
//
#include <hip/hip_runtime.h>

// GCN: 4x [h=(x*ns)@W ; agg=segment_sum(h[src],dst) ; out=agg*nd+b (+relu)]
// N=100000 nodes, E=1.6M edges, feats 128->64->64->64->40, fp32.
// R7: binfill EPT 16 (grid 391, was 196 @ 7.9% occupancy); layer-3 h rows
//     narrowed to 40 floats (160B) with dedicated agg40 gather.

constexpr int BLK = 256;
constexpr int BIN_SHIFT = 7;          // 128 nodes per bin
constexpr int BIN_NODES = 128;
constexpr int BIN_CAP = 3072;         // mean load 2048, generous headroom
constexpr int MAX_NB = 800;           // LDS hist capacity (nb = 782)
constexpr int EPT = 16;               // edges per thread in binfill

__global__ void zero_int(int* p, int n) {
  int i = blockIdx.x * blockDim.x + threadIdx.x;
  if (i < n) p[i] = 0;
}

// ---- single-pass edge binning + out-degree count ----
__global__ __launch_bounds__(BLK) void binfill(const int* __restrict__ src,
                                               const int* __restrict__ dst,
                                               int* __restrict__ deg_out,
                                               int* __restrict__ bin_cnt,
                                               int* __restrict__ codes,
                                               int e, int nb) {
  __shared__ int hist[MAX_NB];
  __shared__ int basec[MAX_NB];
  const int tid = threadIdx.x;
  for (int i = tid; i < nb; i += BLK) hist[i] = 0;
  __syncthreads();

  const int B0 = blockIdx.x * (BLK * EPT);
  int s[EPT], d[EPT];
  #pragma unroll
  for (int c = 0; c < EPT / 4; ++c) {
    int i = B0 + (c * BLK + tid) * 4;
    if (i + 3 < e) {
      int4 sv = *(const int4*)(src + i);
      int4 dv = *(const int4*)(dst + i);
      s[4 * c + 0] = sv.x; s[4 * c + 1] = sv.y;
      s[4 * c + 2] = sv.z; s[4 * c + 3] = sv.w;
      d[4 * c + 0] = dv.x; d[4 * c + 1] = dv.y;
      d[4 * c + 2] = dv.z; d[4 * c + 3] = dv.w;
    } else {
      #pragma unroll
      for (int j = 0; j < 4; ++j) {
        int ii = i + j;
        if (ii < e) { s[4 * c + j] = src[ii]; d[4 * c + j] = dst[ii]; }
        else { s[4 * c + j] = 0; d[4 * c + j] = -1; }
      }
    }
  }

  #pragma unroll
  for (int j = 0; j < EPT; ++j) {
    if (d[j] >= 0) {
      atomicAdd(&deg_out[s[j]], 1);
      atomicAdd(&hist[d[j] >> BIN_SHIFT], 1);
    }
  }
  __syncthreads();
  for (int i = tid; i < nb; i += BLK) {
    int c = hist[i];
    basec[i] = c ? atomicAdd(&bin_cnt[i], c) : 0;
  }
  __syncthreads();
  #pragma unroll
  for (int j = 0; j < EPT; ++j) {
    if (d[j] >= 0) {
      int b = d[j] >> BIN_SHIFT;
      int ofs = atomicAdd(&basec[b], 1);
      if (ofs < BIN_CAP)
        codes[(size_t)b * BIN_CAP + ofs] = ((d[j] & (BIN_NODES - 1)) << 17) | s[j];
    }
  }
}

__global__ void norms_ns(const int* __restrict__ deg_out, float* ns, int n) {
  int i = blockIdx.x * blockDim.x + threadIdx.x;
  if (i < n) {
    int od = deg_out[i];
    ns[i] = od > 0 ? rsqrtf((float)od) : 0.f;
  }
}

// ---- single-block exclusive scan of bin counts -> bin_base; row_ptr[n]=total
__global__ __launch_bounds__(BLK) void scan_bins(const int* __restrict__ bin_cnt,
                                                 int* __restrict__ bin_base,
                                                 int* __restrict__ row_ptr,
                                                 int nb, int n) {
  const int tid = threadIdx.x;
  const int base = tid * 4;
  int v0 = 0, v1 = 0, v2 = 0, v3 = 0;
  if (base + 0 < nb) v0 = min(bin_cnt[base + 0], BIN_CAP);
  if (base + 1 < nb) v1 = min(bin_cnt[base + 1], BIN_CAP);
  if (base + 2 < nb) v2 = min(bin_cnt[base + 2], BIN_CAP);
  if (base + 3 < nb) v3 = min(bin_cnt[base + 3], BIN_CAP);
  int s = v0 + v1 + v2 + v3;
  const int lane = tid & 63, wid = tid >> 6;
  int incl = s;
  #pragma unroll
  for (int off = 1; off < 64; off <<= 1) {
    int t = __shfl_up(incl, off, 64);
    if (lane >= off) incl += t;
  }
  __shared__ int wtot[4];
  if (lane == 63) wtot[wid] = incl;
  __syncthreads();
  int woff = 0;
  for (int w = 0; w < wid; ++w) woff += wtot[w];
  int run = woff + (incl - s);
  if (base + 0 < nb) bin_base[base + 0] = run; run += v0;
  if (base + 1 < nb) bin_base[base + 1] = run; run += v1;
  if (base + 2 < nb) bin_base[base + 2] = run; run += v2;
  if (base + 3 < nb) bin_base[base + 3] = run; run += v3;
  if (tid == BLK - 1) {
    int total = wtot[0] + wtot[1] + wtot[2] + wtot[3];
    bin_base[nb] = total;
    row_ptr[n] = total;
  }
}

// ---- one block per bin: local CSR build + row_ptr + nd ----
__global__ __launch_bounds__(BLK) void bin2csr(const int* __restrict__ codes,
                                               const int* __restrict__ bin_cnt,
                                               const int* __restrict__ bin_base,
                                               int* __restrict__ row_ptr,
                                               float* __restrict__ nd,
                                               int* __restrict__ esrc, int n) {
  __shared__ int scodes[BIN_CAP];
  __shared__ int hist[BIN_NODES];
  __shared__ int rowof[BIN_NODES];
  __shared__ int wsum[2];
  const int tid = threadIdx.x;
  const int bin = blockIdx.x;
  const int cnt = min(bin_cnt[bin], BIN_CAP);
  const int base = bin_base[bin];
  const int* cb = codes + (size_t)bin * BIN_CAP;

  if (tid < BIN_NODES) hist[tid] = 0;
  for (int i = tid; i < cnt; i += BLK) scodes[i] = cb[i];
  __syncthreads();
  for (int i = tid; i < cnt; i += BLK) atomicAdd(&hist[scodes[i] >> 17], 1);
  __syncthreads();

  if (tid < BIN_NODES) {
    int v = hist[tid];
    int incl = v;
    const int lane = tid & 63, wid = tid >> 6;
    #pragma unroll
    for (int off = 1; off < 64; off <<= 1) {
      int t = __shfl_up(incl, off, 64);
      if (lane >= off) incl += t;
    }
    if (lane == 63) wsum[wid] = incl;
    __syncthreads();
    int excl = incl - v + (wid ? wsum[0] : 0);
    rowof[tid] = excl;
    int node = bin * BIN_NODES + tid;
    if (node < n) {
      row_ptr[node] = base + excl;
      nd[node] = v > 0 ? rsqrtf((float)v) : 0.f;
    }
  } else {
    __syncthreads();
  }
  __syncthreads();

  for (int i = tid; i < cnt; i += BLK) {
    int code = scodes[i];
    int pos = atomicAdd(&rowof[code >> 17], 1);
    esrc[base + pos] = code & 0x1FFFF;
  }
}

// ---- h = (x*ns) @ W ; block-tiled GEMM ----
template <int K, int F, int STRIDE>
__global__ __launch_bounds__(BLK) void gemm_tile(const float* __restrict__ x,
                                                 const float* __restrict__ W,
                                                 const float* __restrict__ ns,
                                                 float* __restrict__ h, int n) {
  constexpr int KT = 64;
  constexpr int KP = KT + 4;
  __shared__ float sx[64 * KP];
  __shared__ float sW[KT * F];
  const int tid = threadIdx.x;
  const int n0 = blockIdx.x * 64;
  const int ft = tid & 15, nt = tid >> 4;
  const int fbase = (4 * ft < F) ? 4 * ft : 0;
  float acc[4][4] = {};

  for (int kt = 0; kt < K; kt += KT) {
    if (kt) __syncthreads();
    for (int i = tid; i < KT * F; i += BLK) sW[i] = W[kt * F + i];
    for (int idx = tid; idx < 64 * (KT / 4); idx += BLK) {
      int node = idx >> 4;
      int kk = idx & 15;
      int gn = min(n0 + node, n - 1);
      float4 v = *(const float4*)(x + (size_t)gn * K + kt + kk * 4);
      *(float4*)(sx + node * KP + kk * 4) = v;
    }
    __syncthreads();

    #pragma unroll 4
    for (int k0 = 0; k0 < KT; k0 += 4) {
      float4 xv0 = *(const float4*)(sx + (4 * nt + 0) * KP + k0);
      float4 xv1 = *(const float4*)(sx + (4 * nt + 1) * KP + k0);
      float4 xv2 = *(const float4*)(sx + (4 * nt + 2) * KP + k0);
      float4 xv3 = *(const float4*)(sx + (4 * nt + 3) * KP + k0);
      float4 w0 = *(const float4*)(sW + (k0 + 0) * F + fbase);
      float4 w1 = *(const float4*)(sW + (k0 + 1) * F + fbase);
      float4 w2 = *(const float4*)(sW + (k0 + 2) * F + fbase);
      float4 w3 = *(const float4*)(sW + (k0 + 3) * F + fbase);
#define GCN_STEP(C, WV)                                                  \
      acc[0][0] = fmaf(xv0.C, WV.x, acc[0][0]);                          \
      acc[0][1] = fmaf(xv0.C, WV.y, acc[0][1]);                          \
      acc[0][2] = fmaf(xv0.C, WV.z, acc[0][2]);                          \
      acc[0][3] = fmaf(xv0.C, WV.w, acc[0][3]);                          \
      acc[1][0] = fmaf(xv1.C, WV.x, acc[1][0]);                          \
      acc[1][1] = fmaf(xv1.C, WV.y, acc[1][1]);                          \
      acc[1][2] = fmaf(xv1.C, WV.z, acc[1][2]);                          \
      acc[1][3] = fmaf(xv1.C, WV.w, acc[1][3]);                          \
      acc[2][0] = fmaf(xv2.C, WV.x, acc[2][0]);                          \
      acc[2][1] = fmaf(xv2.C, WV.y, acc[2][1]);                          \
      acc[2][2] = fmaf(xv2.C, WV.z, acc[2][2]);                          \
      acc[2][3] = fmaf(xv2.C, WV.w, acc[2][3]);                          \
      acc[3][0] = fmaf(xv3.C, WV.x, acc[3][0]);                          \
      acc[3][1] = fmaf(xv3.C, WV.y, acc[3][1]);                          \
      acc[3][2] = fmaf(xv3.C, WV.z, acc[3][2]);                          \
      acc[3][3] = fmaf(xv3.C, WV.w, acc[3][3]);
      GCN_STEP(x, w0)
      GCN_STEP(y, w1)
      GCN_STEP(z, w2)
      GCN_STEP(w, w3)
#undef GCN_STEP
    }
  }

  #pragma unroll
  for (int i = 0; i < 4; ++i) {
    int node = n0 + 4 * nt + i;
    if (node < n) {
      float s = ns[node];
      if (4 * ft < F) {
        float4 o;
        o.x = acc[i][0] * s; o.y = acc[i][1] * s;
        o.z = acc[i][2] * s; o.w = acc[i][3] * s;
        *(float4*)(h + (size_t)node * STRIDE + 4 * ft) = o;
      } else if (4 * ft < STRIDE) {
        *(float4*)(h + (size_t)node * STRIDE + 4 * ft) = float4{0.f, 0.f, 0.f, 0.f};
      }
    }
  }
}

// ---- agg: 4 edges per wave-iteration; h rows are stride-64 fp32. ----
template <bool RELU, int OUTF>
__global__ void agg4(const float* __restrict__ h, const int* __restrict__ row_ptr,
                     const int* __restrict__ esrc, const float* __restrict__ nd,
                     const float* __restrict__ b, float* __restrict__ out, int n) {
  int tid = threadIdx.x;
  int node = blockIdx.x * 4 + (tid >> 6);
  if (node >= n) return;
  int lane = tid & 63;
  int g = lane >> 4;
  int fl = lane & 15;
  int beg = row_ptr[node], end = row_ptr[node + 1];
  float ax = 0.f, ay = 0.f, az = 0.f, aw = 0.f;
  #pragma unroll 4
  for (int k = beg + g; k < end; k += 4) {
    int s = esrc[k];
    float4 v = *(const float4*)(h + (size_t)s * 64 + fl * 4);
    ax += v.x; ay += v.y; az += v.z; aw += v.w;
  }
  ax += __shfl_xor(ax, 16, 64); ay += __shfl_xor(ay, 16, 64);
  az += __shfl_xor(az, 16, 64); aw += __shfl_xor(aw, 16, 64);
  ax += __shfl_xor(ax, 32, 64); ay += __shfl_xor(ay, 32, 64);
  az += __shfl_xor(az, 32, 64); aw += __shfl_xor(aw, 32, 64);
  if (lane < OUTF / 4) {
    float ndv = nd[node];
    float4 bv = ((const float4*)b)[fl];
    float4 o;
    o.x = ax * ndv + bv.x;
    o.y = ay * ndv + bv.y;
    o.z = az * ndv + bv.z;
    o.w = aw * ndv + bv.w;
    if (RELU) {
      o.x = fmaxf(o.x, 0.f); o.y = fmaxf(o.y, 0.f);
      o.z = fmaxf(o.z, 0.f); o.w = fmaxf(o.w, 0.f);
    }
    *(float4*)(out + (size_t)node * OUTF + fl * 4) = o;
  }
}

// ---- final agg on narrow 40-float (160B) h rows; no relu ----
__global__ void agg40(const float* __restrict__ h, const int* __restrict__ row_ptr,
                      const int* __restrict__ esrc, const float* __restrict__ nd,
                      const float* __restrict__ b, float* __restrict__ out, int n) {
  int tid = threadIdx.x;
  int node = blockIdx.x * 4 + (tid >> 6);
  if (node >= n) return;
  int lane = tid & 63;
  int g = lane >> 4;
  int fl = lane & 15;
  int beg = row_ptr[node], end = row_ptr[node + 1];
  float ax = 0.f, ay = 0.f, az = 0.f, aw = 0.f;
  if (fl < 10) {
    #pragma unroll 4
    for (int k = beg + g; k < end; k += 4) {
      int s = esrc[k];
      float4 v = *(const float4*)(h + (size_t)s * 40 + fl * 4);
      ax += v.x; ay += v.y; az += v.z; aw += v.w;
    }
  }
  ax += __shfl_xor(ax, 16, 64); ay += __shfl_xor(ay, 16, 64);
  az += __shfl_xor(az, 16, 64); aw += __shfl_xor(aw, 16, 64);
  ax += __shfl_xor(ax, 32, 64); ay += __shfl_xor(ay, 32, 64);
  az += __shfl_xor(az, 32, 64); aw += __shfl_xor(aw, 32, 64);
  if (lane < 10) {
    float ndv = nd[node];
    float4 bv = ((const float4*)b)[fl];
    float4 o;
    o.x = ax * ndv + bv.x;
    o.y = ay * ndv + bv.y;
    o.z = az * ndv + bv.z;
    o.w = aw * ndv + bv.w;
    *(float4*)(out + (size_t)node * 40 + fl * 4) = o;
  }
}

extern "C" void kernel_launch(void* const* d_in, const int* in_sizes, int n_in,
                              void* d_out, int out_size, void* d_ws, size_t ws_size,
                              hipStream_t stream) {
  const float* features = (const float*)d_in[0];
  const int* src = (const int*)d_in[1];
  const int* dst = (const int*)d_in[2];
  const float* W0 = (const float*)d_in[3];
  const float* b0 = (const float*)d_in[4];
  const float* W1 = (const float*)d_in[5];
  const float* b1 = (const float*)d_in[6];
  const float* W2 = (const float*)d_in[7];
  const float* b2 = (const float*)d_in[8];
  const float* W3 = (const float*)d_in[9];
  const float* b3 = (const float*)d_in[10];

  const int n = in_sizes[0] / 128;  // 100000
  const int e = in_sizes[1];        // 1600000
  const int nb = (n + BIN_NODES - 1) >> BIN_SHIFT;  // 782

  char* p = (char*)d_ws;
  auto alloc = [&](size_t bytes) {
    void* q = (void*)p;
    p += (bytes + 255) & ~(size_t)255;
    return q;
  };
  int* deg_out = (int*)alloc((size_t)(n + nb) * 4);  // deg_out + bin_cnt
  int* bin_cnt = deg_out + n;
  float* ns = (float*)alloc((size_t)n * 4);
  float* nd = (float*)alloc((size_t)n * 4);
  int* bin_base = (int*)alloc((size_t)(nb + 1) * 4);
  int* row_ptr = (int*)alloc((size_t)(n + 1) * 4);
  int* codes = (int*)alloc((size_t)nb * BIN_CAP * 4);
  int* esrc = (int*)alloc((size_t)e * 4);
  float* h = (float*)alloc((size_t)n * 64 * 4);
  float* xb = (float*)alloc((size_t)n * 64 * 4);

  zero_int<<<(n + nb + BLK - 1) / BLK, BLK, 0, stream>>>(deg_out, n + nb);
  binfill<<<(e + BLK * EPT - 1) / (BLK * EPT), BLK, 0, stream>>>(
      src, dst, deg_out, bin_cnt, codes, e, nb);
  norms_ns<<<(n + BLK - 1) / BLK, BLK, 0, stream>>>(deg_out, ns, n);
  scan_bins<<<1, BLK, 0, stream>>>(bin_cnt, bin_base, row_ptr, nb, n);
  bin2csr<<<nb, BLK, 0, stream>>>(codes, bin_cnt, bin_base, row_ptr, nd, esrc, n);

  const int gnode = (n + 3) / 4;   // agg: 4 nodes (waves) per block
  const int gblk = (n + 63) / 64;  // gemm_tile: 64 nodes per block

  // layer 0: 128 -> 64, relu
  gemm_tile<128, 64, 64><<<gblk, BLK, 0, stream>>>(features, W0, ns, h, n);
  agg4<true, 64><<<gnode, BLK, 0, stream>>>(h, row_ptr, esrc, nd, b0, xb, n);
  // layer 1: 64 -> 64, relu
  gemm_tile<64, 64, 64><<<gblk, BLK, 0, stream>>>(xb, W1, ns, h, n);
  agg4<true, 64><<<gnode, BLK, 0, stream>>>(h, row_ptr, esrc, nd, b1, xb, n);
  // layer 2: 64 -> 64, relu
  gemm_tile<64, 64, 64><<<gblk, BLK, 0, stream>>>(xb, W2, ns, h, n);
  agg4<true, 64><<<gnode, BLK, 0, stream>>>(h, row_ptr, esrc, nd, b2, xb, n);
  // layer 3: 64 -> 40, no relu; h rows narrow (40 floats, 160B)
  gemm_tile<64, 40, 40><<<gblk, BLK, 0, stream>>>(xb, W3, ns, h, n);
  agg40<<<gnode, BLK, 0, stream>>>(h, row_ptr, esrc, nd, b3, (float*)d_out, n);
}